// Round 1
// baseline (1322.803 us; speedup 1.0000x reference)
//
#include <hip/hip_runtime.h>
#include <hip/hip_bf16.h>
#include <cstdint>
#include <cstddef>

#define AS1 __attribute__((address_space(1)))
#define AS3 __attribute__((address_space(3)))

constexpr int HIDC   = 4096;
constexpr int INTERC = 11008;
constexpr int NTOKC  = 4096;          // B*S = 2*2048
constexpr int NWGU   = 2 * INTERC;    // 22016 weight columns in gate_up

using f32x4 = __attribute__((ext_vector_type(4))) float;
using s16x8 = __attribute__((ext_vector_type(8))) short;   // 8 bf16 in 4 VGPRs

__device__ __forceinline__ short f2bf(float f) {
  __hip_bfloat16 h = __float2bfloat16(f);
  return __builtin_bit_cast(short, h);
}

// ---------------- prologue kernels ----------------

// x f32 -> bf16 (vectorized)
__global__ void cvt_x_kernel(const float4* __restrict__ x, ushort4* __restrict__ xb, int n4) {
  int stride = gridDim.x * blockDim.x;
  for (int i = blockIdx.x * blockDim.x + threadIdx.x; i < n4; i += stride) {
    float4 v = x[i];
    ushort4 o;
    o.x = (unsigned short)f2bf(v.x);
    o.y = (unsigned short)f2bf(v.y);
    o.z = (unsigned short)f2bf(v.z);
    o.w = (unsigned short)f2bf(v.w);
    xb[i] = o;
  }
}

// repack qweight [K][N/8] (nibbles along N) -> qt [N][K/8] (nibbles along K)
// qt[n][kk] nibble j = W[kk*8+j][n]
__global__ void repack_kernel(const uint32_t* __restrict__ qw, uint32_t* __restrict__ qt,
                              int kints, int Wn) {
  long total  = (long)Wn * kints;
  long stride = (long)gridDim.x * blockDim.x;
  for (long idx = blockIdx.x * (long)blockDim.x + threadIdx.x; idx < total; idx += stride) {
    int col = (int)(idx / kints);
    int kk  = (int)(idx - (long)col * kints);
    uint32_t ow[8] = {0, 0, 0, 0, 0, 0, 0, 0};
#pragma unroll
    for (int j = 0; j < 8; ++j) {
      uint32_t v = qw[(size_t)(kk * 8 + j) * Wn + col];
#pragma unroll
      for (int jn = 0; jn < 8; ++jn)
        ow[jn] |= ((v >> (4 * jn)) & 0xFu) << (4 * j);
    }
#pragma unroll
    for (int jn = 0; jn < 8; ++jn)
      qt[(size_t)(col * 8 + jn) * kints + kk] = ow[jn];
  }
}

// tab[g][n] = (s, -z*s)  so w = fma(nibble, s, -z*s)
__global__ void mktab_kernel(const uint32_t* __restrict__ qz, const float* __restrict__ sc,
                             float2* __restrict__ tab, int total, int Nw) {
  int stride = gridDim.x * blockDim.x;
  for (int idx = blockIdx.x * blockDim.x + threadIdx.x; idx < total; idx += stride) {
    int g = idx / Nw, n = idx - g * Nw;
    uint32_t z = (qz[(size_t)g * (Nw >> 3) + (n >> 3)] >> ((n & 7) * 4)) & 0xFu;
    float s = sc[idx];
    tab[idx] = make_float2(s, -s * (float)z);
  }
}

// ---------------- fused dequant GEMM ----------------
// DUAL=1: gate_up GEMM (dual accumulators, SiLU*mul epilogue, bf16 h out), N-tile=64
// DUAL=0: down GEMM (f32 out), N-tile=128
// BM=128, BK=64, 256 threads (4 waves, 2x2).
// LDS: A tile [128][64] bf16 @0 (16KB), B tile(s) [rows][64] bf16 @16KB (16KB).
// XOR swizzle on the 128B rows: byte ^= (row&7)<<4  (both A and B, write+read sides).
template <int DUAL, int KSTEPS, int KINTS, int NWTOT>
__global__ __launch_bounds__(256, 2) void qgemm_kernel(
    const __hip_bfloat16* __restrict__ A, const uint32_t* __restrict__ QT,
    const float2* __restrict__ TAB, __hip_bfloat16* __restrict__ Hout,
    float* __restrict__ Fout) {
  constexpr int K  = KSTEPS * 64;
  constexpr int NI = DUAL ? 2 : 4;
  __shared__ __align__(16) char lds[32768];

  const int tid  = threadIdx.x;
  const int lane = tid & 63;
  const int w    = tid >> 6;
  const int wr   = w >> 1, wc = w & 1;
  const int fr   = lane & 15;
  const int fq   = lane >> 4;
  const int nt   = blockIdx.x, mt = blockIdx.y;
  const int row0 = mt * 128;

  // A staging: linear LDS slot o holds logical element (r, b^((r&7)<<4)).
  // global_load_lds dest = wave-uniform base + lane*16, so pre-swizzle the SOURCE.
  int a_src[4];
#pragma unroll
  for (int i = 0; i < 4; ++i) {
    int o = i * 4096 + tid * 16;
    int r = o >> 7;
    int b = (o & 127) ^ ((r & 7) << 4);
    a_src[i] = (row0 + r) * K + (b >> 1);
  }

  // B staging coords: each thread owns one weight row (n) and half its BK span (32 k).
  int s_mat, s_nl, s_kh, s_nglob;
  if (DUAL) {
    s_mat = tid >> 7;            // 0=gate, 1=up
    int tt = tid & 127;
    s_nl  = tt >> 1;             // 0..63
    s_kh  = tt & 1;
    s_nglob = nt * 64 + s_nl + (s_mat ? INTERC : 0);
  } else {
    s_mat = 0;
    s_nl  = tid >> 1;            // 0..127
    s_kh  = tid & 1;
    s_nglob = nt * 128 + s_nl;
  }
  char* bdst = lds + 16384 + s_mat * 8192 + s_nl * 128;
  const int bswz = (s_nl & 7) << 4;

  f32x4 acc0[4][NI] = {};
  f32x4 acc1[4][NI] = {};   // DCE'd when !DUAL

#pragma unroll 1
  for (int kt = 0; kt < KSTEPS; ++kt) {
    if (kt) __syncthreads();   // protect LDS from previous compute readers

    // --- A stage: 4x global_load_lds width 16 ---
#pragma unroll
    for (int i = 0; i < 4; ++i) {
      const __hip_bfloat16* src = A + a_src[i] + kt * 64;
      __builtin_amdgcn_global_load_lds((const AS1 uint32_t*)src,
                                       (AS3 uint32_t*)(lds + i * 4096 + w * 1024),
                                       16, 0, 0);
    }

    // --- B stage: load 4 packed int32 (32 nibbles along K), dequant, ds_write_b128 ---
    {
      const int g = kt >> 1;   // BK=64, group=128 -> group constant per tile
      const uint32_t* qp = QT + (size_t)s_nglob * KINTS + kt * 8 + s_kh * 4;
      uint4 q = *(const uint4*)qp;
      float2 sz = TAB[(size_t)g * NWTOT + s_nglob];
      uint32_t qq[4] = {q.x, q.y, q.z, q.w};
#pragma unroll
      for (int ii = 0; ii < 4; ++ii) {
        s16x8 wv;
#pragma unroll
        for (int j = 0; j < 8; ++j) {
          float v = (float)((qq[ii] >> (4 * j)) & 0xFu);
          wv[j] = f2bf(fmaf(v, sz.x, sz.y));
        }
        *(s16x8*)(bdst + ((s_kh * 64 + ii * 16) ^ bswz)) = wv;
      }
    }
    __syncthreads();   // compiler drains vmcnt(0)+lgkmcnt(0) before s_barrier

    // --- compute: 2 x K=32 MFMA sub-steps ---
#pragma unroll
    for (int kk = 0; kk < 2; ++kk) {
      const int bb = (((kk << 2) | fq) ^ (fr & 7)) << 4;  // swizzled k-byte
      s16x8 av[4];
#pragma unroll
      for (int mi = 0; mi < 4; ++mi)
        av[mi] = *(const s16x8*)(lds + (wr * 64 + mi * 16 + fr) * 128 + bb);
      if (DUAL) {
#pragma unroll
        for (int ni = 0; ni < 2; ++ni) {
          const int brow = (wc * 32 + ni * 16 + fr) * 128 + bb;
          s16x8 bg = *(const s16x8*)(lds + 16384 + brow);
          s16x8 bu = *(const s16x8*)(lds + 24576 + brow);
#pragma unroll
          for (int mi = 0; mi < 4; ++mi) {
            acc0[mi][ni] = __builtin_amdgcn_mfma_f32_16x16x32_bf16(av[mi], bg, acc0[mi][ni], 0, 0, 0);
            acc1[mi][ni] = __builtin_amdgcn_mfma_f32_16x16x32_bf16(av[mi], bu, acc1[mi][ni], 0, 0, 0);
          }
        }
      } else {
#pragma unroll
        for (int ni = 0; ni < 4; ++ni) {
          s16x8 bv = *(const s16x8*)(lds + 16384 + (wc * 64 + ni * 16 + fr) * 128 + bb);
#pragma unroll
          for (int mi = 0; mi < 4; ++mi)
            acc0[mi][ni] = __builtin_amdgcn_mfma_f32_16x16x32_bf16(av[mi], bv, acc0[mi][ni], 0, 0, 0);
        }
      }
    }
  }

  // --- epilogue ---  C/D map: col = lane&15, row = (lane>>4)*4 + reg  [m89-verified]
  if (DUAL) {
    const int col0 = nt * 64 + wc * 32;
#pragma unroll
    for (int mi = 0; mi < 4; ++mi) {
      const int rr = row0 + wr * 64 + mi * 16 + fq * 4;
#pragma unroll
      for (int ni = 0; ni < NI; ++ni) {
        const int cc = col0 + ni * 16 + fr;
#pragma unroll
        for (int r = 0; r < 4; ++r) {
          float gv = acc0[mi][ni][r];
          float uv = acc1[mi][ni][r];
          float hv = gv / (1.0f + __expf(-gv)) * uv;   // silu(g)*u
          Hout[(size_t)(rr + r) * INTERC + cc] = __float2bfloat16(hv);
        }
      }
    }
  } else {
    const int col0 = nt * 128 + wc * 64;
#pragma unroll
    for (int mi = 0; mi < 4; ++mi) {
      const int rr = row0 + wr * 64 + mi * 16 + fq * 4;
#pragma unroll
      for (int ni = 0; ni < NI; ++ni) {
        const int cc = col0 + ni * 16 + fr;
#pragma unroll
        for (int r = 0; r < 4; ++r)
          Fout[(size_t)(rr + r) * HIDC + cc] = acc0[mi][ni][r];
      }
    }
  }
}

// ---------------- launch ----------------
extern "C" void kernel_launch(void* const* d_in, const int* in_sizes, int n_in,
                              void* d_out, int out_size, void* d_ws, size_t ws_size,
                              hipStream_t stream) {
  const float*    x     = (const float*)d_in[0];
  const uint32_t* qw_gu = (const uint32_t*)d_in[1];
  const uint32_t* qz_gu = (const uint32_t*)d_in[2];
  const float*    sc_gu = (const float*)d_in[3];
  const uint32_t* qw_dn = (const uint32_t*)d_in[4];
  const uint32_t* qz_dn = (const uint32_t*)d_in[5];
  const float*    sc_dn = (const float*)d_in[6];
  float* out = (float*)d_out;

  // workspace layout (bytes), all 256-aligned; total ~199.9 MB
  char* ws = (char*)d_ws;
  __hip_bfloat16* xb   = (__hip_bfloat16*)(ws + 0);           // 33,554,432  x bf16
  uint32_t*       qtgu = (uint32_t*)(ws + 33554432);          // 45,088,768  repacked gu
  uint32_t*       qtdn = (uint32_t*)(ws + 78643200);          // 22,544,384  repacked dn
  float2*         tgu  = (float2*)(ws + 101187584);           //  5,636,096  (s,-zs) gu
  float2*         tdn  = (float2*)(ws + 106823680);           //  2,818,048  (s,-zs) dn
  __hip_bfloat16* hbuf = (__hip_bfloat16*)(ws + 109641728);   // 90,177,536  h bf16

  cvt_x_kernel<<<2048, 256, 0, stream>>>((const float4*)x, (ushort4*)xb, NTOKC * HIDC / 4);
  repack_kernel<<<2048, 256, 0, stream>>>(qw_gu, qtgu, HIDC / 8, NWGU / 8);
  repack_kernel<<<2048, 256, 0, stream>>>(qw_dn, qtdn, INTERC / 8, HIDC / 8);
  mktab_kernel<<<1024, 256, 0, stream>>>(qz_gu, sc_gu, tgu, (HIDC / 128) * NWGU, NWGU);
  mktab_kernel<<<1024, 256, 0, stream>>>(qz_dn, sc_dn, tdn, (INTERC / 128) * HIDC, HIDC);

  // GEMM1: [4096 x 4096] @ dequant(W_gu) -> silu*mul -> h bf16 [4096 x 11008]
  qgemm_kernel<1, 64, 512, NWGU>
      <<<dim3(INTERC / 64, NTOKC / 128), 256, 0, stream>>>(xb, qtgu, tgu, hbuf, nullptr);
  // GEMM2: h @ dequant(W_dn) -> out f32 [4096 x 4096]
  qgemm_kernel<0, 172, 1376, HIDC>
      <<<dim3(HIDC / 128, NTOKC / 128), 256, 0, stream>>>(hbuf, qtdn, tdn, nullptr, out);
}